// Round 6
// baseline (248.183 us; speedup 1.0000x reference)
//
#include <hip/hip_runtime.h>
#include <hip/hip_bf16.h>
#include <math.h>

#define B_ 4
#define N_ 2048
#define D_ 512
#define H_ 8
// NORM * log2(e): scores pre-scaled so softmax uses exp2 directly.
#define NORM2_ 0.18033688011112042f

typedef __attribute__((ext_vector_type(8))) short short8;   // 8 bf16 (4 VGPRs)
typedef __attribute__((ext_vector_type(4))) float f32x4;    // MFMA C/D
#define MFMA16(a, b, c) __builtin_amdgcn_mfma_f32_16x16x32_bf16(a, b, c, 0, 0, 0)
#define EXP2(x) __builtin_amdgcn_exp2f(x)

// pack two f32 -> two bf16 (RNE, native v_cvt_pk_bf16_f32); .x at low half
static __device__ __forceinline__ uint32_t pk2(float lo, float hi) {
  __hip_bfloat162 h = __float22bfloat162_rn(make_float2(lo, hi));
  return *(reinterpret_cast<uint32_t*>(&h));
}

// async global->LDS, 16B per lane. LDS dest must be wave-uniform base + lane*16.
static __device__ __forceinline__ void async16(const ushort* lds, const ushort* g) {
  __builtin_amdgcn_global_load_lds(
      (const __attribute__((address_space(1))) uint32_t*)g,
      (__attribute__((address_space(3))) uint32_t*)(ushort*)lds, 16, 0, 0);
}

// ---------------- fused prep: byte keep-mask + all fp32->bf16 conversions ----------------
__global__ __launch_bounds__(256) void prep(const float* __restrict__ q,
                                            const int* __restrict__ mask,
                                            const float* __restrict__ wq,
                                            const float* __restrict__ wk,
                                            const float* __restrict__ wc,
                                            ushort* __restrict__ Xb,
                                            ushort* __restrict__ Wb,
                                            uint32_t* __restrict__ mb) {
  const int bx = blockIdx.x;
  if (bx < 2048) {
    // keep-mask bytes: 0xFF = keep, 0x00 = masked. 16.8 MB total.
    const int gid = (bx << 8) + threadIdx.x;
    for (int i = gid; i < 4194304; i += 524288) {
      const int4 m = ((const int4*)mask)[i];
      const uint32_t v = (m.x ? 0u : 0xFFu) | (m.y ? 0u : 0xFF00u) |
                         (m.z ? 0u : 0xFF0000u) | (m.w ? 0u : 0xFF000000u);
      mb[i] = v;
    }
  } else if (bx < 3072) {
    const int i = ((bx - 2048) << 8) + threadIdx.x;
    for (int j = i; j < 1048576; j += 262144) {
      const float4 v = ((const float4*)q)[j];
      uint2 o; o.x = pk2(v.x, v.y); o.y = pk2(v.z, v.w);
      ((uint2*)Xb)[j] = o;
    }
  } else {
    const int i = ((bx - 3072) << 8) + threadIdx.x;
    for (int j = i; j < 196608; j += 24576) {
      const int wi = j >> 16, off = j & 65535;
      const float* src = (wi == 0) ? wq : (wi == 1) ? wk : wc;
      const float4 v = ((const float4*)src)[off];
      uint2 o; o.x = pk2(v.x, v.y); o.y = pk2(v.z, v.w);
      ((uint2*)Wb)[j] = o;
    }
  }
}

// ---------------- 128x128 bf16 MFMA GEMM: C = X @ W^T ----------------
template <int F32OUT>
__global__ __launch_bounds__(256) void gemm128(const ushort* __restrict__ X,
                                               const ushort* __restrict__ W0,
                                               const ushort* __restrict__ W1,
                                               void* __restrict__ C0,
                                               void* __restrict__ C1,
                                               float s0, float s1) {
  const ushort* Wp = (blockIdx.z == 0) ? W0 : W1;
  void* Cp = (blockIdx.z == 0) ? C0 : C1;
  const float sc = (blockIdx.z == 0) ? s0 : s1;
  const int t = threadIdx.x;
  const int w = t >> 6, lane = t & 63, quad = lane >> 4, c = lane & 15;
  const int wm = w & 1, wn = w >> 1;
  const int n0 = blockIdx.x * 128, m0 = blockIdx.y * 128;
  __shared__ __align__(16) ushort Xs[128][64];
  __shared__ __align__(16) ushort Ws[128][64];
  f32x4 acc[4][4];
#pragma unroll
  for (int i = 0; i < 4; ++i)
#pragma unroll
    for (int j = 0; j < 4; ++j) acc[i][j] = (f32x4){0.f, 0.f, 0.f, 0.f};

  for (int k0 = 0; k0 < D_; k0 += 64) {
    __syncthreads();
#pragma unroll
    for (int g = 0; g < 4; ++g) {
      const int id = w * 256 + g * 64 + lane;
      const int row = id >> 3, lch = id & 7;
      const int gch = lch ^ (row & 7);
      async16(&Xs[row][lch * 8], X + (size_t)(m0 + row) * D_ + k0 + gch * 8);
      async16(&Ws[row][lch * 8], Wp + (size_t)(n0 + row) * D_ + k0 + gch * 8);
    }
    __syncthreads();
#pragma unroll
    for (int s = 0; s < 2; ++s) {
      short8 af[4], bt[4];
#pragma unroll
      for (int i = 0; i < 4; ++i) {
        const int rA = wn * 64 + i * 16 + c;
        af[i] = *(const short8*)&Ws[rA][(((s * 4 + quad) ^ (rA & 7)) & 7) * 8];
        const int rB = wm * 64 + i * 16 + c;
        bt[i] = *(const short8*)&Xs[rB][(((s * 4 + quad) ^ (rB & 7)) & 7) * 8];
      }
#pragma unroll
      for (int i = 0; i < 4; ++i)
#pragma unroll
        for (int j = 0; j < 4; ++j) acc[i][j] = MFMA16(af[i], bt[j], acc[i][j]);
    }
  }
#pragma unroll
  for (int i = 0; i < 4; ++i)
#pragma unroll
    for (int j = 0; j < 4; ++j) {
      const size_t off =
          (size_t)(m0 + wm * 64 + j * 16 + c) * D_ + n0 + wn * 64 + i * 16 + quad * 4;
      if (F32OUT) {
        float4 v; v.x = acc[i][j][0]; v.y = acc[i][j][1]; v.z = acc[i][j][2]; v.w = acc[i][j][3];
        *(float4*)((float*)Cp + off) = v;
      } else {
        uint2 uv;
        uv.x = pk2(acc[i][j][0] * sc, acc[i][j][1] * sc);
        uv.y = pk2(acc[i][j][2] * sc, acc[i][j][3] * sc);
        *(uint2*)((ushort*)Cp + off) = uv;
      }
    }
}

// ---------------- flash attention: bf16 MFMA, V == K, no online max ----------------
// Changes vs round 5 (latency-stall theory):
//  (a) Ks/KtU double-buffered -> ONE barrier per tile; stage of tile kt+1
//      (ds_writes from prefetch regs) overlaps compute of tile kt.
//  (b) s_setprio removed (lockstep waves: T5 prereq absent, m190 evidence).
//  Kept: byte keep-mask AND (r5-verified), chunked XCD swizzle.
__global__ __launch_bounds__(256) void attn_mfma(const ushort* __restrict__ Qb,
                                                 const ushort* __restrict__ Kb,
                                                 const unsigned char* __restrict__ mb,
                                                 ushort* __restrict__ Ab) {
  const int Lx = blockIdx.x;                       // 0..1023
  const int wk = ((Lx & 7) << 7) | (Lx >> 3);      // chunked XCD swizzle (bijective)
  const int h = wk & 7, qt64 = (wk >> 3) & 31, b = wk >> 8;
  const int q0 = qt64 * 64;
  const int t = threadIdx.x;
  const int w = t >> 6, lane = t & 63, quad = lane >> 4, c = lane & 15;

  __shared__ __align__(16) ushort Ks[2][64][64];     // 16K: K rows dbuf, swizzled
  __shared__ __align__(16) uint32_t KtU[2][64][32];  // 16K: V^T key-pair u32 dbuf
  __shared__ __align__(16) ushort QP[4][16][72];     // 9.2K: Qs (staging) then Pq
  ushort(*Qs)[64] = (ushort(*)[64]) & QP[0][0][0];
  ushort(*Pq)[16][72] = QP;

  // ---- stage Q once (async DMA) ----
#pragma unroll
  for (int p = 0; p < 2; ++p) {
    const int id = t + p * 256;
    const int row = id >> 3, lch = id & 7, gch = lch ^ (row & 7);
    async16(&Qs[row][lch * 8], Qb + (size_t)(b * N_ + q0 + row) * D_ + h * 64 + gch * 8);
  }

  // ---- staging roles + tile-0 data ----
  const int kp = t >> 3, ch = t & 7;  // staging role: key-pair, d-chunk
  const int r0 = 2 * kp, r1 = r0 + 1;
  const int ksw0 = ((ch ^ (r0 & 7)) & 7) * 8, ksw1 = ((ch ^ (r1 & 7)) & 7) * 8;
  const ushort* kb0 = Kb + (size_t)(b * N_ + 2 * kp) * D_ + h * 64 + ch * 8;
  const uint32_t* mrow =
      (const uint32_t*)(mb + (size_t)(b * N_ + q0 + (w << 4) + c) * N_) + quad;

  uint4 c0 = *(const uint4*)kb0;        // tile 0
  uint4 c1 = *(const uint4*)(kb0 + D_);
  uint32_t cm[4], nxm[4];
#pragma unroll
  for (int tI = 0; tI < 4; ++tI) cm[tI] = mrow[(tI & 1) * 4 + (tI >> 1) * 8];
  __syncthreads();  // Q DMA complete

  // ---- Q fragments ----
  const int rq = (w << 4) + c;
  const short8 bq0 = *(const short8*)&Qs[rq][((quad ^ (rq & 7)) & 7) * 8];
  const short8 bq1 = *(const short8*)&Qs[rq][(((4 + quad) ^ (rq & 7)) & 7) * 8];

  // ---- stage tile 0 into buf 0; load tile 1 into regs ----
#define STAGE(bf)                                                               \
  do {                                                                          \
    *(uint4*)&Ks[bf][r0][ksw0] = c0;                                            \
    *(uint4*)&Ks[bf][r1][ksw1] = c1;                                            \
    const uint32_t* a0 = (const uint32_t*)&c0;                                  \
    const uint32_t* a1 = (const uint32_t*)&c1;                                  \
    _Pragma("unroll") for (int m = 0; m < 4; ++m) {                             \
      const uint32_t lo = __builtin_amdgcn_perm(a1[m], a0[m], 0x05040100);      \
      const uint32_t hi = __builtin_amdgcn_perm(a1[m], a0[m], 0x07060302);      \
      const int j0 = 2 * m, j1 = 2 * m + 1;                                     \
      KtU[bf][ch * 8 + j0][(kp & 3) | ((((kp >> 2) ^ j0 ^ ch) & 7) << 2)] = lo; \
      KtU[bf][ch * 8 + j1][(kp & 3) | ((((kp >> 2) ^ j1 ^ ch) & 7) << 2)] = hi; \
    }                                                                           \
  } while (0)

  STAGE(0);
  {
    const ushort* kbn = kb0 + (size_t)64 * D_;
    c0 = *(const uint4*)kbn;            // tile 1
    c1 = *(const uint4*)(kbn + D_);
  }

  short8 vones;
#pragma unroll
  for (int i = 0; i < 8; ++i) vones[i] = (short)0x3F80;  // bf16 1.0 splat

  f32x4 o[4];
#pragma unroll
  for (int i = 0; i < 4; ++i) o[i] = (f32x4){0.f, 0.f, 0.f, 0.f};
  f32x4 o5 = (f32x4){0.f, 0.f, 0.f, 0.f};  // l accumulator (ones-MFMA)

  uint4 nx0, nx1;
  const int NT = N_ / 64;
  for (int kt = 0; kt < NT; ++kt) {
    const int p = kt & 1;
    __syncthreads();  // buf[p] staged (prev region) visible; prev reads of buf[p^1] done
    // ---- stage tile kt+1 into buf[p^1] (overlaps compute below) ----
    if (kt + 1 < NT) STAGE(p ^ 1);
    // ---- prefetch: tile kt+2 K data, tile kt+1 masks ----
    if (kt + 2 < NT) {
      const ushort* kbn = kb0 + (size_t)(kt + 2) * 64 * D_;
      nx0 = *(const uint4*)kbn;
      nx1 = *(const uint4*)(kbn + D_);
    }
    if (kt + 1 < NT) {
#pragma unroll
      for (int tI = 0; tI < 4; ++tI)
        nxm[tI] = mrow[(kt + 1) * 16 + (tI & 1) * 4 + (tI >> 1) * 8];
    }

    // ---- S^T = K·Q^T; p = exp2(s) AND keep-mask (packed bf16) ----
#pragma unroll
    for (int tI = 0; tI < 4; ++tI) {
      const int rk = tI * 16 + c;
      const short8 aK0 = *(const short8*)&Ks[p][rk][((quad ^ (rk & 7)) & 7) * 8];
      const short8 aK1 = *(const short8*)&Ks[p][rk][(((4 + quad) ^ (rk & 7)) & 7) * 8];
      f32x4 z = (f32x4){0.f, 0.f, 0.f, 0.f};
      z = MFMA16(aK0, bq0, z);
      z = MFMA16(aK1, bq1, z);
      const uint32_t mw = cm[tI];
      const uint32_t mlo = __builtin_amdgcn_perm(mw, mw, 0x01010000);  // keys r=0,1
      const uint32_t mhi = __builtin_amdgcn_perm(mw, mw, 0x03030202);  // keys r=2,3
      uint32_t pb[4];
#pragma unroll
      for (int r = 0; r < 4; ++r) pb[r] = __float_as_uint(EXP2(z[r]));
      const uint32_t pw0 = __builtin_amdgcn_perm(pb[1], pb[0], 0x07060302) & mlo;
      const uint32_t pw1 = __builtin_amdgcn_perm(pb[3], pb[2], 0x07060302) & mhi;
      *(uint2*)&Pq[w][c][tI * 16 + quad * 4] = make_uint2(pw0, pw1);
    }

    // ---- O^T += V^T·P^T ; l via ones-MFMA ----
    const short8 bp0 = *(const short8*)&Pq[w][c][quad * 8];
    const short8 bp1 = *(const short8*)&Pq[w][c][32 + quad * 8];
    o5 = MFMA16(vones, bp0, o5);
    o5 = MFMA16(vones, bp1, o5);
#pragma unroll
    for (int dt = 0; dt < 4; ++dt) {
      const int dd = dt * 16 + c;
      const int g = (c & 7) ^ ((2 * dt + (c >> 3)) & 7);
      const short8 aV0 = *(const short8*)&KtU[p][dd][((quad ^ g) & 7) << 2];
      const short8 aV1 = *(const short8*)&KtU[p][dd][(((4 + quad) ^ g) & 7) << 2];
      o[dt] = MFMA16(aV0, bp0, o[dt]);
      o[dt] = MFMA16(aV1, bp1, o[dt]);
    }

    if (kt + 2 < NT) { c0 = nx0; c1 = nx1; }
    if (kt + 1 < NT) {
#pragma unroll
      for (int tI = 0; tI < 4; ++tI) cm[tI] = nxm[tI];
    }
  }
#undef STAGE

  // ---- epilogue: O^T[d][q] / l (l = o5[0], all rows equal; no shuffles) ----
  const float inv = 1.f / o5[0];
#pragma unroll
  for (int dt = 0; dt < 4; ++dt) {
    uint2 uv;
    uv.x = pk2(o[dt][0] * inv, o[dt][1] * inv);
    uv.y = pk2(o[dt][2] * inv, o[dt][3] * inv);
    *(uint2*)(Ab + (size_t)(b * N_ + q0 + (w << 4) + c) * D_ + h * 64 + dt * 16 + quad * 4) = uv;
  }
}

extern "C" void kernel_launch(void* const* d_in, const int* in_sizes, int n_in,
                              void* d_out, int out_size, void* d_ws, size_t ws_size,
                              hipStream_t stream) {
  const float* queries = (const float*)d_in[0];
  const int* mask = (const int*)d_in[1];
  const float* Wq = (const float*)d_in[2];
  const float* Wk = (const float*)d_in[3];
  const float* Wc = (const float*)d_in[4];
  float* out = (float*)d_out;

  const size_t nTok = (size_t)B_ * N_;
  const size_t nXD = nTok * D_;
  const size_t nW = (size_t)D_ * D_;
  ushort* Xb = (ushort*)d_ws;
  ushort* Wqb = Xb + nXD;     // Wq|Wk|Wc contiguous
  ushort* Wkb = Wqb + nW;
  ushort* Wcb = Wkb + nW;
  ushort* Qb = Wcb + nW;
  ushort* Kb = Qb + nXD;
  ushort* Ab = Kb + nXD;
  uint32_t* mb = (uint32_t*)(Ab + nXD);  // byte keep-mask, 16.8 MB

  prep<<<3168, 256, 0, stream>>>(queries, mask, Wq, Wk, Wc, Xb, Wqb, mb);
  gemm128<0><<<dim3(D_ / 128, (int)(nTok / 128), 2), 256, 0, stream>>>(
      Xb, Wqb, Wkb, Qb, Kb, NORM2_, 1.0f);
  attn_mfma<<<dim3(N_ / 64 * H_ * B_), 256, 0, stream>>>(
      Qb, Kb, (const unsigned char*)mb, Ab);
  gemm128<1><<<dim3(D_ / 128, (int)(nTok / 128), 1), 256, 0, stream>>>(
      Ab, Wcb, nullptr, out, nullptr, 1.0f, 1.0f);
}

// Round 8
// 214.747 us; speedup vs baseline: 1.1557x; 1.1557x over previous
//
#include <hip/hip_runtime.h>
#include <hip/hip_bf16.h>
#include <math.h>

#define B_ 4
#define N_ 2048
#define D_ 512
#define H_ 8
// NORM * log2(e): scores pre-scaled so softmax uses exp2 directly.
#define NORM2_ 0.18033688011112042f

typedef __attribute__((ext_vector_type(8))) short short8;   // 8 bf16 (4 VGPRs)
typedef __attribute__((ext_vector_type(4))) float f32x4;    // MFMA C/D
#define MFMA16(a, b, c) __builtin_amdgcn_mfma_f32_16x16x32_bf16(a, b, c, 0, 0, 0)
#define EXP2(x) __builtin_amdgcn_exp2f(x)

// pack two f32 -> two bf16 (RNE, native v_cvt_pk_bf16_f32); .x at low half
static __device__ __forceinline__ uint32_t pk2(float lo, float hi) {
  __hip_bfloat162 h = __float22bfloat162_rn(make_float2(lo, hi));
  return *(reinterpret_cast<uint32_t*>(&h));
}

// async global->LDS, 16B per lane. LDS dest must be wave-uniform base + lane*16.
static __device__ __forceinline__ void async16(const ushort* lds, const ushort* g) {
  __builtin_amdgcn_global_load_lds(
      (const __attribute__((address_space(1))) uint32_t*)g,
      (__attribute__((address_space(3))) uint32_t*)(ushort*)lds, 16, 0, 0);
}

// ---------------- fused prep: mask pack + all fp32->bf16 conversions (r1-verified) -----------
__global__ __launch_bounds__(256) void prep(const float* __restrict__ q,
                                            const int* __restrict__ mask,
                                            const float* __restrict__ wq,
                                            const float* __restrict__ wk,
                                            const float* __restrict__ wc,
                                            ushort* __restrict__ Xb,
                                            ushort* __restrict__ Wb,
                                            uint32_t* __restrict__ pk) {
  const int bx = blockIdx.x;
  if (bx < 2048) {
    const int lane = threadIdx.x & 63;
    const int wid = ((bx << 8) + threadIdx.x) >> 6;  // 8192 waves
    for (int i = wid; i < 65536; i += 8192) {        // 256-key chunks
      const int4 m = ((const int4*)mask)[(size_t)i * 64 + lane];
      uint32_t nib = (uint32_t)(m.x != 0) | ((uint32_t)(m.y != 0) << 1) |
                     ((uint32_t)(m.z != 0) << 2) | ((uint32_t)(m.w != 0) << 3);
      nib |= __shfl_xor(nib, 1) << 4;
      nib |= __shfl_xor(nib, 2) << 8;
      nib |= __shfl_xor(nib, 4) << 16;
      if ((lane & 7) == 0) pk[i * 8 + (lane >> 3)] = nib;
    }
  } else if (bx < 3072) {
    const int i = ((bx - 2048) << 8) + threadIdx.x;
    for (int j = i; j < 1048576; j += 262144) {
      const float4 v = ((const float4*)q)[j];
      uint2 o; o.x = pk2(v.x, v.y); o.y = pk2(v.z, v.w);
      ((uint2*)Xb)[j] = o;
    }
  } else {
    const int i = ((bx - 3072) << 8) + threadIdx.x;
    for (int j = i; j < 196608; j += 24576) {
      const int wi = j >> 16, off = j & 65535;
      const float* src = (wi == 0) ? wq : (wi == 1) ? wk : wc;
      const float4 v = ((const float4*)src)[off];
      uint2 o; o.x = pk2(v.x, v.y); o.y = pk2(v.z, v.w);
      ((uint2*)Wb)[j] = o;
    }
  }
}

// ---------------- merge: Ab = bf16((P0 + P1) / (l0 + l1)), in-place over P1 ----------------
__global__ __launch_bounds__(256) void merge(const ushort* __restrict__ P0,
                                             const float* __restrict__ l0,
                                             const float* __restrict__ l1,
                                             ushort* __restrict__ Ab) {
  const int j = (blockIdx.x << 8) + threadIdx.x;  // 0..524287, 8 bf16 each
  const int h = (j >> 3) & 7;
  const int tok = j >> 6;                          // b*N + n
  const int b = tok >> 11, n = tok & 2047;
  const int li = ((b * H_ + h) << 11) + n;
  const float inv = 1.f / (l0[li] + l1[li]);
  const uint4 a0 = ((const uint4*)P0)[j];
  const uint4 a1 = ((const uint4*)Ab)[j];  // P1 aliases Ab
  uint4 o;
  const uint32_t* u0 = (const uint32_t*)&a0;
  const uint32_t* u1 = (const uint32_t*)&a1;
  uint32_t* uo = (uint32_t*)&o;
#pragma unroll
  for (int m = 0; m < 4; ++m) {
    const float lo = __uint_as_float(u0[m] << 16) + __uint_as_float(u1[m] << 16);
    const float hi = __uint_as_float(u0[m] & 0xFFFF0000u) +
                     __uint_as_float(u1[m] & 0xFFFF0000u);
    uo[m] = pk2(lo * inv, hi * inv);
  }
  ((uint4*)Ab)[j] = o;
}

// ---------------- 128x128 bf16 MFMA GEMM: C = X @ W^T ----------------
template <int F32OUT>
__global__ __launch_bounds__(256) void gemm128(const ushort* __restrict__ X,
                                               const ushort* __restrict__ W0,
                                               const ushort* __restrict__ W1,
                                               void* __restrict__ C0,
                                               void* __restrict__ C1,
                                               float s0, float s1) {
  const ushort* Wp = (blockIdx.z == 0) ? W0 : W1;
  void* Cp = (blockIdx.z == 0) ? C0 : C1;
  const float sc = (blockIdx.z == 0) ? s0 : s1;
  const int t = threadIdx.x;
  const int w = t >> 6, lane = t & 63, quad = lane >> 4, c = lane & 15;
  const int wm = w & 1, wn = w >> 1;
  const int n0 = blockIdx.x * 128, m0 = blockIdx.y * 128;
  __shared__ __align__(16) ushort Xs[128][64];
  __shared__ __align__(16) ushort Ws[128][64];
  f32x4 acc[4][4];
#pragma unroll
  for (int i = 0; i < 4; ++i)
#pragma unroll
    for (int j = 0; j < 4; ++j) acc[i][j] = (f32x4){0.f, 0.f, 0.f, 0.f};

  for (int k0 = 0; k0 < D_; k0 += 64) {
    __syncthreads();
#pragma unroll
    for (int g = 0; g < 4; ++g) {
      const int id = w * 256 + g * 64 + lane;
      const int row = id >> 3, lch = id & 7;
      const int gch = lch ^ (row & 7);
      async16(&Xs[row][lch * 8], X + (size_t)(m0 + row) * D_ + k0 + gch * 8);
      async16(&Ws[row][lch * 8], Wp + (size_t)(n0 + row) * D_ + k0 + gch * 8);
    }
    __syncthreads();
#pragma unroll
    for (int s = 0; s < 2; ++s) {
      short8 af[4], bt[4];
#pragma unroll
      for (int i = 0; i < 4; ++i) {
        const int rA = wn * 64 + i * 16 + c;
        af[i] = *(const short8*)&Ws[rA][(((s * 4 + quad) ^ (rA & 7)) & 7) * 8];
        const int rB = wm * 64 + i * 16 + c;
        bt[i] = *(const short8*)&Xs[rB][(((s * 4 + quad) ^ (rB & 7)) & 7) * 8];
      }
#pragma unroll
      for (int i = 0; i < 4; ++i)
#pragma unroll
        for (int j = 0; j < 4; ++j) acc[i][j] = MFMA16(af[i], bt[j], acc[i][j]);
    }
  }
#pragma unroll
  for (int i = 0; i < 4; ++i)
#pragma unroll
    for (int j = 0; j < 4; ++j) {
      const size_t off =
          (size_t)(m0 + wm * 64 + j * 16 + c) * D_ + n0 + wn * 64 + i * 16 + quad * 4;
      if (F32OUT) {
        float4 v; v.x = acc[i][j][0]; v.y = acc[i][j][1]; v.z = acc[i][j][2]; v.w = acc[i][j][3];
        *(float4*)((float*)Cp + off) = v;
      } else {
        uint2 uv;
        uv.x = pk2(acc[i][j][0] * sc, acc[i][j][1] * sc);
        uv.y = pk2(acc[i][j][2] * sc, acc[i][j][3] * sc);
        *(uint2*)((ushort*)Cp + off) = uv;
      }
    }
}

// ---------------- flash attention: r1 core (verified 73.6us), key-split x2 ----------------
// Block (qt64, hf, h, b): 64 q x keys [hf*1024, (hf+1)*1024) = 16 tiles.
// Inner loop byte-identical to r1 (bit-mask pk, single buffer, 2 barriers/tile,
// no setprio, no swizzle). Epilogue stores PARTIAL O as bf16 to P[hf] and
// partial l (f32) -- each cell written exactly once, no atomics. merge divides.
__global__ __launch_bounds__(256) void attn_mfma(const ushort* __restrict__ Qb,
                                                 const ushort* __restrict__ Kb,
                                                 const uint32_t* __restrict__ pk,
                                                 ushort* __restrict__ P0,
                                                 ushort* __restrict__ P1,
                                                 float* __restrict__ l0,
                                                 float* __restrict__ l1) {
  const int qt64 = blockIdx.x >> 1, hf = blockIdx.x & 1;
  const int h = blockIdx.y, b = blockIdx.z;
  const int q0 = qt64 * 64;
  const int t = threadIdx.x;
  const int w = t >> 6, lane = t & 63, quad = lane >> 4, c = lane & 15;

  __shared__ __align__(16) ushort Ks[64][64];        // 8K: K rows, swizzled chunks
  __shared__ __align__(16) uint32_t KtU[64][32];     // 8K: V^T key-pair u32, swizzled
  __shared__ __align__(16) ushort QP[4][16][72];     // 9.2K: Qs (staging) then Pq
  ushort(*Qs)[64] = (ushort(*)[64]) & QP[0][0][0];
  ushort(*Pq)[16][72] = QP;

  // ---- stage Q once (async DMA) ----
#pragma unroll
  for (int p = 0; p < 2; ++p) {
    const int id = t + p * 256;
    const int row = id >> 3, lch = id & 7, gch = lch ^ (row & 7);
    async16(&Qs[row][lch * 8], Qb + (size_t)(b * N_ + q0 + row) * D_ + h * 64 + gch * 8);
  }
  __syncthreads();
  const int rq = (w << 4) + c;
  const short8 bq0 = *(const short8*)&Qs[rq][((quad ^ (rq & 7)) & 7) * 8];
  const short8 bq1 = *(const short8*)&Qs[rq][(((4 + quad) ^ (rq & 7)) & 7) * 8];

  short8 vones;
#pragma unroll
  for (int i = 0; i < 8; ++i) vones[i] = (short)0x3F80;  // bf16 1.0 splat

  f32x4 o[4];
#pragma unroll
  for (int i = 0; i < 4; ++i) o[i] = (f32x4){0.f, 0.f, 0.f, 0.f};
  f32x4 o5 = (f32x4){0.f, 0.f, 0.f, 0.f};  // l accumulator (ones-MFMA, rows identical)

  const int kp = t >> 3, ch = t & 7;  // staging role: key-pair, d-chunk
  const int r0 = 2 * kp, r1 = r0 + 1;
  const int ksw0 = ((ch ^ (r0 & 7)) & 7) * 8, ksw1 = ((ch ^ (r1 & 7)) & 7) * 8;
  const ushort* kb0 =
      Kb + (size_t)(b * N_ + hf * 1024 + 2 * kp) * D_ + h * 64 + ch * 8;
  const uint32_t* pkq =
      pk + ((size_t)(b * N_ + q0 + (w << 4) + c) << 6) + hf * 32;

  // prefetched tile data (registers)
  uint4 c0 = *(const uint4*)kb0;
  uint4 c1 = *(const uint4*)(kb0 + D_);
  uint2 cm = *(const uint2*)pkq;
  uint4 nx0, nx1; uint2 nxm;

  const int NT = 16;  // half the keys
  for (int kt = 0; kt < NT; ++kt) {
    __syncthreads();  // prior tile's frag reads (and initial Qs reads) done
    // ---- stage K tile from registers (rows + u32 key-pair transpose) ----
    *(uint4*)&Ks[r0][ksw0] = c0;
    *(uint4*)&Ks[r1][ksw1] = c1;
    const uint32_t* a0 = (const uint32_t*)&c0;
    const uint32_t* a1 = (const uint32_t*)&c1;
#pragma unroll
    for (int m = 0; m < 4; ++m) {
      const uint32_t lo = __builtin_amdgcn_perm(a1[m], a0[m], 0x05040100);  // even d
      const uint32_t hi = __builtin_amdgcn_perm(a1[m], a0[m], 0x07060302);  // odd d
      const int j0 = 2 * m, j1 = 2 * m + 1;
      KtU[ch * 8 + j0][(kp & 3) | ((((kp >> 2) ^ j0 ^ ch) & 7) << 2)] = lo;
      KtU[ch * 8 + j1][(kp & 3) | ((((kp >> 2) ^ j1 ^ ch) & 7) << 2)] = hi;
    }
    __syncthreads();

    if (kt + 1 < NT) {  // prefetch next tile while computing
      const ushort* kbn = kb0 + (size_t)(kt + 1) * 64 * D_;
      nx0 = *(const uint4*)kbn;
      nx1 = *(const uint4*)(kbn + D_);
      nxm = *(const uint2*)(pkq + (kt + 1) * 2);
    }

    // ---- S^T = K·Q^T; p = masked ? 0 : exp2(s) ----
#pragma unroll
    for (int tI = 0; tI < 4; ++tI) {
      const int rk = tI * 16 + c;
      const short8 aK0 = *(const short8*)&Ks[rk][((quad ^ (rk & 7)) & 7) * 8];
      const short8 aK1 = *(const short8*)&Ks[rk][(((4 + quad) ^ (rk & 7)) & 7) * 8];
      f32x4 z = (f32x4){0.f, 0.f, 0.f, 0.f};
      z = MFMA16(aK0, bq0, z);
      z = MFMA16(aK1, bq1, z);
      const uint32_t mw = (tI < 2) ? cm.x : cm.y;
      const int bb = ((tI & 1) << 4) + quad * 4;
      uint32_t pb[4];
#pragma unroll
      for (int r = 0; r < 4; ++r) {
        const float e = EXP2(z[r]);                       // unconditional
        pb[r] = ((mw >> (bb + r)) & 1u) ? 0u : __float_as_uint(e);
      }
      const uint32_t pw0 = __builtin_amdgcn_perm(pb[1], pb[0], 0x07060302);
      const uint32_t pw1 = __builtin_amdgcn_perm(pb[3], pb[2], 0x07060302);
      *(uint2*)&Pq[w][c][tI * 16 + quad * 4] = make_uint2(pw0, pw1);
    }

    // ---- O^T += V^T·P^T ; l via ones-MFMA ----
    const short8 bp0 = *(const short8*)&Pq[w][c][quad * 8];
    const short8 bp1 = *(const short8*)&Pq[w][c][32 + quad * 8];
    o5 = MFMA16(vones, bp0, o5);
    o5 = MFMA16(vones, bp1, o5);
#pragma unroll
    for (int dt = 0; dt < 4; ++dt) {
      const int dd = dt * 16 + c;
      const int g = (c & 7) ^ ((2 * dt + (c >> 3)) & 7);
      const short8 aV0 = *(const short8*)&KtU[dd][((quad ^ g) & 7) << 2];
      const short8 aV1 = *(const short8*)&KtU[dd][(((4 + quad) ^ g) & 7) << 2];
      o[dt] = MFMA16(aV0, bp0, o[dt]);
      o[dt] = MFMA16(aV1, bp1, o[dt]);
    }

    if (kt + 1 < NT) { c0 = nx0; c1 = nx1; cm = nxm; }
  }

  // ---- epilogue: store PARTIAL O^T (bf16, unscaled) + partial l; no atomics ----
  ushort* Pp = hf ? P1 : P0;
  float* lp = hf ? l1 : l0;
#pragma unroll
  for (int dt = 0; dt < 4; ++dt) {
    uint2 uv;
    uv.x = pk2(o[dt][0], o[dt][1]);
    uv.y = pk2(o[dt][2], o[dt][3]);
    *(uint2*)(Pp + (size_t)(b * N_ + q0 + (w << 4) + c) * D_ + h * 64 + dt * 16 + quad * 4) = uv;
  }
  if (quad == 0) lp[((b * H_ + h) << 11) + q0 + (w << 4) + c] = o5[0];
}

extern "C" void kernel_launch(void* const* d_in, const int* in_sizes, int n_in,
                              void* d_out, int out_size, void* d_ws, size_t ws_size,
                              hipStream_t stream) {
  const float* queries = (const float*)d_in[0];
  const int* mask = (const int*)d_in[1];
  const float* Wq = (const float*)d_in[2];
  const float* Wk = (const float*)d_in[3];
  const float* Wc = (const float*)d_in[4];
  float* out = (float*)d_out;

  const size_t nTok = (size_t)B_ * N_;
  const size_t nXD = nTok * D_;
  const size_t nW = (size_t)D_ * D_;
  ushort* Xb = (ushort*)d_ws;
  ushort* Wqb = Xb + nXD;     // Wq|Wk|Wc contiguous
  ushort* Wkb = Wqb + nW;
  ushort* Wcb = Wkb + nW;
  ushort* Qb = Wcb + nW;
  ushort* Kb = Qb + nXD;
  ushort* Ab = Kb + nXD;
  uint32_t* pk = (uint32_t*)(Ab + nXD);
  // dead-region reuse during attn (all within verified footprint):
  ushort* P0 = Xb;            // bf16 partial O, half 0 (Xb dead after gemm<0>)
  ushort* P1 = Ab;            // bf16 partial O, half 1 (merged in-place into Ab)
  float* l0 = (float*)Wqb;    // 256 KB in dead Wqb (512 KB)
  float* l1 = (float*)Wkb;    // 256 KB in dead Wkb

  prep<<<3168, 256, 0, stream>>>(queries, mask, Wq, Wk, Wc, Xb, Wqb, pk);
  gemm128<0><<<dim3(D_ / 128, (int)(nTok / 128), 2), 256, 0, stream>>>(
      Xb, Wqb, Wkb, Qb, Kb, NORM2_, 1.0f);
  attn_mfma<<<dim3(64, H_, B_), 256, 0, stream>>>(Qb, Kb, pk, P0, P1, l0, l1);
  merge<<<2048, 256, 0, stream>>>(P0, l0, l1, Ab);
  gemm128<1><<<dim3(D_ / 128, (int)(nTok / 128), 1), 256, 0, stream>>>(
      Ab, Wcb, nullptr, out, nullptr, 1.0f, 1.0f);
}

// Round 9
// 209.596 us; speedup vs baseline: 1.1841x; 1.0246x over previous
//
#include <hip/hip_runtime.h>
#include <hip/hip_bf16.h>
#include <math.h>

#define B_ 4
#define N_ 2048
#define D_ 512
#define H_ 8
// NORM * log2(e): scores pre-scaled so softmax uses exp2 directly.
#define NORM2_ 0.18033688011112042f

typedef __attribute__((ext_vector_type(8))) short short8;   // 8 bf16 (4 VGPRs)
typedef __attribute__((ext_vector_type(4))) float f32x4;    // MFMA C/D
#define MFMA16(a, b, c) __builtin_amdgcn_mfma_f32_16x16x32_bf16(a, b, c, 0, 0, 0)
#define EXP2(x) __builtin_amdgcn_exp2f(x)

// pack two f32 -> two bf16 (RNE, native v_cvt_pk_bf16_f32); .x at low half
static __device__ __forceinline__ uint32_t pk2(float lo, float hi) {
  __hip_bfloat162 h = __float22bfloat162_rn(make_float2(lo, hi));
  return *(reinterpret_cast<uint32_t*>(&h));
}

// async global->LDS, 16B per lane. LDS dest must be wave-uniform base + lane*16.
static __device__ __forceinline__ void async16(const ushort* lds, const ushort* g) {
  __builtin_amdgcn_global_load_lds(
      (const __attribute__((address_space(1))) uint32_t*)g,
      (__attribute__((address_space(3))) uint32_t*)(ushort*)lds, 16, 0, 0);
}

// ---------------- fused prep: mask pack + all fp32->bf16 conversions (r1-verified) -----------
__global__ __launch_bounds__(256) void prep(const float* __restrict__ q,
                                            const int* __restrict__ mask,
                                            const float* __restrict__ wq,
                                            const float* __restrict__ wk,
                                            const float* __restrict__ wc,
                                            ushort* __restrict__ Xb,
                                            ushort* __restrict__ Wb,
                                            uint32_t* __restrict__ pk) {
  const int bx = blockIdx.x;
  if (bx < 2048) {
    const int lane = threadIdx.x & 63;
    const int wid = ((bx << 8) + threadIdx.x) >> 6;  // 8192 waves
    for (int i = wid; i < 65536; i += 8192) {        // 256-key chunks
      const int4 m = ((const int4*)mask)[(size_t)i * 64 + lane];
      uint32_t nib = (uint32_t)(m.x != 0) | ((uint32_t)(m.y != 0) << 1) |
                     ((uint32_t)(m.z != 0) << 2) | ((uint32_t)(m.w != 0) << 3);
      nib |= __shfl_xor(nib, 1) << 4;
      nib |= __shfl_xor(nib, 2) << 8;
      nib |= __shfl_xor(nib, 4) << 16;
      if ((lane & 7) == 0) pk[i * 8 + (lane >> 3)] = nib;
    }
  } else if (bx < 3072) {
    const int i = ((bx - 2048) << 8) + threadIdx.x;
    for (int j = i; j < 1048576; j += 262144) {
      const float4 v = ((const float4*)q)[j];
      uint2 o; o.x = pk2(v.x, v.y); o.y = pk2(v.z, v.w);
      ((uint2*)Xb)[j] = o;
    }
  } else {
    const int i = ((bx - 3072) << 8) + threadIdx.x;
    for (int j = i; j < 196608; j += 24576) {
      const int wi = j >> 16, off = j & 65535;
      const float* src = (wi == 0) ? wq : (wi == 1) ? wk : wc;
      const float4 v = ((const float4*)src)[off];
      uint2 o; o.x = pk2(v.x, v.y); o.y = pk2(v.z, v.w);
      ((uint2*)Wb)[j] = o;
    }
  }
}

// ---------------- merge: Ab = bf16((P0 + P1) / (l0 + l1)), in-place over P1 ----------------
__global__ __launch_bounds__(256) void merge(const ushort* __restrict__ P0,
                                             const float* __restrict__ l0,
                                             const float* __restrict__ l1,
                                             ushort* __restrict__ Ab) {
  const int j = (blockIdx.x << 8) + threadIdx.x;  // 0..524287, 8 bf16 each
  const int h = (j >> 3) & 7;
  const int tok = j >> 6;                          // b*N + n
  const int b = tok >> 11, n = tok & 2047;
  const int li = ((b * H_ + h) << 11) + n;
  const float inv = 1.f / (l0[li] + l1[li]);
  const uint4 a0 = ((const uint4*)P0)[j];
  const uint4 a1 = ((const uint4*)Ab)[j];  // P1 aliases Ab
  uint4 o;
  const uint32_t* u0 = (const uint32_t*)&a0;
  const uint32_t* u1 = (const uint32_t*)&a1;
  uint32_t* uo = (uint32_t*)&o;
#pragma unroll
  for (int m = 0; m < 4; ++m) {
    const float lo = __uint_as_float(u0[m] << 16) + __uint_as_float(u1[m] << 16);
    const float hi = __uint_as_float(u0[m] & 0xFFFF0000u) +
                     __uint_as_float(u1[m] & 0xFFFF0000u);
    uo[m] = pk2(lo * inv, hi * inv);
  }
  ((uint4*)Ab)[j] = o;
}

// ---------------- 128x128 bf16 MFMA GEMM: C = X @ W^T ----------------
// 2-phase pipeline (guide T3 minimal recipe): double-buffered LDS, STAGE(t+1)
// issued BEFORE compute of tile t, ONE __syncthreads per K-iter (its implicit
// vmcnt drain lands a prefetch issued ~a full MFMA phase earlier).
template <int F32OUT>
__global__ __launch_bounds__(256) void gemm128(const ushort* __restrict__ X,
                                               const ushort* __restrict__ W0,
                                               const ushort* __restrict__ W1,
                                               void* __restrict__ C0,
                                               void* __restrict__ C1,
                                               float s0, float s1) {
  const ushort* Wp = (blockIdx.z == 0) ? W0 : W1;
  void* Cp = (blockIdx.z == 0) ? C0 : C1;
  const float sc = (blockIdx.z == 0) ? s0 : s1;
  const int t = threadIdx.x;
  const int w = t >> 6, lane = t & 63, quad = lane >> 4, c = lane & 15;
  const int wm = w & 1, wn = w >> 1;
  const int n0 = blockIdx.x * 128, m0 = blockIdx.y * 128;
  __shared__ __align__(16) ushort Xs[2][128][64];
  __shared__ __align__(16) ushort Ws[2][128][64];
  f32x4 acc[4][4];
#pragma unroll
  for (int i = 0; i < 4; ++i)
#pragma unroll
    for (int j = 0; j < 4; ++j) acc[i][j] = (f32x4){0.f, 0.f, 0.f, 0.f};

#define GSTAGE(bf, k0)                                                        \
  do {                                                                        \
    _Pragma("unroll") for (int g = 0; g < 4; ++g) {                           \
      const int id = w * 256 + g * 64 + lane;                                 \
      const int row = id >> 3, lch = id & 7;                                  \
      const int gch = lch ^ (row & 7);                                        \
      async16(&Xs[bf][row][lch * 8], X + (size_t)(m0 + row) * D_ + (k0) + gch * 8); \
      async16(&Ws[bf][row][lch * 8], Wp + (size_t)(n0 + row) * D_ + (k0) + gch * 8); \
    }                                                                         \
  } while (0)

  GSTAGE(0, 0);
  __syncthreads();  // buf0 landed (implicit vmcnt drain)
  const int NK = D_ / 64;  // 8
  for (int kt = 0; kt < NK; ++kt) {
    const int bf = kt & 1;
    if (kt + 1 < NK) GSTAGE(bf ^ 1, (kt + 1) * 64);  // prefetch next (hidden under MFMA)
#pragma unroll
    for (int s = 0; s < 2; ++s) {
      short8 af[4], bt[4];
#pragma unroll
      for (int i = 0; i < 4; ++i) {
        const int rA = wn * 64 + i * 16 + c;
        af[i] = *(const short8*)&Ws[bf][rA][(((s * 4 + quad) ^ (rA & 7)) & 7) * 8];
        const int rB = wm * 64 + i * 16 + c;
        bt[i] = *(const short8*)&Xs[bf][rB][(((s * 4 + quad) ^ (rB & 7)) & 7) * 8];
      }
#pragma unroll
      for (int i = 0; i < 4; ++i)
#pragma unroll
        for (int j = 0; j < 4; ++j) acc[i][j] = MFMA16(af[i], bt[j], acc[i][j]);
    }
    if (kt + 1 < NK) __syncthreads();  // drain prefetch + protect buf reuse
  }
#undef GSTAGE
#pragma unroll
  for (int i = 0; i < 4; ++i)
#pragma unroll
    for (int j = 0; j < 4; ++j) {
      const size_t off =
          (size_t)(m0 + wm * 64 + j * 16 + c) * D_ + n0 + wn * 64 + i * 16 + quad * 4;
      if (F32OUT) {
        float4 v; v.x = acc[i][j][0]; v.y = acc[i][j][1]; v.z = acc[i][j][2]; v.w = acc[i][j][3];
        *(float4*)((float*)Cp + off) = v;
      } else {
        uint2 uv;
        uv.x = pk2(acc[i][j][0] * sc, acc[i][j][1] * sc);
        uv.y = pk2(acc[i][j][2] * sc, acc[i][j][3] * sc);
        *(uint2*)((ushort*)Cp + off) = uv;
      }
    }
}

// ---------------- flash attention: r8-verified core, key-split x2 (UNCHANGED) ----------------
__global__ __launch_bounds__(256) void attn_mfma(const ushort* __restrict__ Qb,
                                                 const ushort* __restrict__ Kb,
                                                 const uint32_t* __restrict__ pk,
                                                 ushort* __restrict__ P0,
                                                 ushort* __restrict__ P1,
                                                 float* __restrict__ l0,
                                                 float* __restrict__ l1) {
  const int qt64 = blockIdx.x >> 1, hf = blockIdx.x & 1;
  const int h = blockIdx.y, b = blockIdx.z;
  const int q0 = qt64 * 64;
  const int t = threadIdx.x;
  const int w = t >> 6, lane = t & 63, quad = lane >> 4, c = lane & 15;

  __shared__ __align__(16) ushort Ks[64][64];        // 8K: K rows, swizzled chunks
  __shared__ __align__(16) uint32_t KtU[64][32];     // 8K: V^T key-pair u32, swizzled
  __shared__ __align__(16) ushort QP[4][16][72];     // 9.2K: Qs (staging) then Pq
  ushort(*Qs)[64] = (ushort(*)[64]) & QP[0][0][0];
  ushort(*Pq)[16][72] = QP;

  // ---- stage Q once (async DMA) ----
#pragma unroll
  for (int p = 0; p < 2; ++p) {
    const int id = t + p * 256;
    const int row = id >> 3, lch = id & 7, gch = lch ^ (row & 7);
    async16(&Qs[row][lch * 8], Qb + (size_t)(b * N_ + q0 + row) * D_ + h * 64 + gch * 8);
  }
  __syncthreads();
  const int rq = (w << 4) + c;
  const short8 bq0 = *(const short8*)&Qs[rq][((quad ^ (rq & 7)) & 7) * 8];
  const short8 bq1 = *(const short8*)&Qs[rq][(((4 + quad) ^ (rq & 7)) & 7) * 8];

  short8 vones;
#pragma unroll
  for (int i = 0; i < 8; ++i) vones[i] = (short)0x3F80;  // bf16 1.0 splat

  f32x4 o[4];
#pragma unroll
  for (int i = 0; i < 4; ++i) o[i] = (f32x4){0.f, 0.f, 0.f, 0.f};
  f32x4 o5 = (f32x4){0.f, 0.f, 0.f, 0.f};  // l accumulator (ones-MFMA, rows identical)

  const int kp = t >> 3, ch = t & 7;  // staging role: key-pair, d-chunk
  const int r0 = 2 * kp, r1 = r0 + 1;
  const int ksw0 = ((ch ^ (r0 & 7)) & 7) * 8, ksw1 = ((ch ^ (r1 & 7)) & 7) * 8;
  const ushort* kb0 =
      Kb + (size_t)(b * N_ + hf * 1024 + 2 * kp) * D_ + h * 64 + ch * 8;
  const uint32_t* pkq =
      pk + ((size_t)(b * N_ + q0 + (w << 4) + c) << 6) + hf * 32;

  // prefetched tile data (registers)
  uint4 c0 = *(const uint4*)kb0;
  uint4 c1 = *(const uint4*)(kb0 + D_);
  uint2 cm = *(const uint2*)pkq;
  uint4 nx0, nx1; uint2 nxm;

  const int NT = 16;  // half the keys
  for (int kt = 0; kt < NT; ++kt) {
    __syncthreads();  // prior tile's frag reads (and initial Qs reads) done
    // ---- stage K tile from registers (rows + u32 key-pair transpose) ----
    *(uint4*)&Ks[r0][ksw0] = c0;
    *(uint4*)&Ks[r1][ksw1] = c1;
    const uint32_t* a0 = (const uint32_t*)&c0;
    const uint32_t* a1 = (const uint32_t*)&c1;
#pragma unroll
    for (int m = 0; m < 4; ++m) {
      const uint32_t lo = __builtin_amdgcn_perm(a1[m], a0[m], 0x05040100);  // even d
      const uint32_t hi = __builtin_amdgcn_perm(a1[m], a0[m], 0x07060302);  // odd d
      const int j0 = 2 * m, j1 = 2 * m + 1;
      KtU[ch * 8 + j0][(kp & 3) | ((((kp >> 2) ^ j0 ^ ch) & 7) << 2)] = lo;
      KtU[ch * 8 + j1][(kp & 3) | ((((kp >> 2) ^ j1 ^ ch) & 7) << 2)] = hi;
    }
    __syncthreads();

    if (kt + 1 < NT) {  // prefetch next tile while computing
      const ushort* kbn = kb0 + (size_t)(kt + 1) * 64 * D_;
      nx0 = *(const uint4*)kbn;
      nx1 = *(const uint4*)(kbn + D_);
      nxm = *(const uint2*)(pkq + (kt + 1) * 2);
    }

    // ---- S^T = K·Q^T; p = masked ? 0 : exp2(s) ----
#pragma unroll
    for (int tI = 0; tI < 4; ++tI) {
      const int rk = tI * 16 + c;
      const short8 aK0 = *(const short8*)&Ks[rk][((quad ^ (rk & 7)) & 7) * 8];
      const short8 aK1 = *(const short8*)&Ks[rk][(((4 + quad) ^ (rk & 7)) & 7) * 8];
      f32x4 z = (f32x4){0.f, 0.f, 0.f, 0.f};
      z = MFMA16(aK0, bq0, z);
      z = MFMA16(aK1, bq1, z);
      const uint32_t mw = (tI < 2) ? cm.x : cm.y;
      const int bb = ((tI & 1) << 4) + quad * 4;
      uint32_t pb[4];
#pragma unroll
      for (int r = 0; r < 4; ++r) {
        const float e = EXP2(z[r]);                       // unconditional
        pb[r] = ((mw >> (bb + r)) & 1u) ? 0u : __float_as_uint(e);
      }
      const uint32_t pw0 = __builtin_amdgcn_perm(pb[1], pb[0], 0x07060302);
      const uint32_t pw1 = __builtin_amdgcn_perm(pb[3], pb[2], 0x07060302);
      *(uint2*)&Pq[w][c][tI * 16 + quad * 4] = make_uint2(pw0, pw1);
    }

    // ---- O^T += V^T·P^T ; l via ones-MFMA ----
    const short8 bp0 = *(const short8*)&Pq[w][c][quad * 8];
    const short8 bp1 = *(const short8*)&Pq[w][c][32 + quad * 8];
    o5 = MFMA16(vones, bp0, o5);
    o5 = MFMA16(vones, bp1, o5);
#pragma unroll
    for (int dt = 0; dt < 4; ++dt) {
      const int dd = dt * 16 + c;
      const int g = (c & 7) ^ ((2 * dt + (c >> 3)) & 7);
      const short8 aV0 = *(const short8*)&KtU[dd][((quad ^ g) & 7) << 2];
      const short8 aV1 = *(const short8*)&KtU[dd][(((4 + quad) ^ g) & 7) << 2];
      o[dt] = MFMA16(aV0, bp0, o[dt]);
      o[dt] = MFMA16(aV1, bp1, o[dt]);
    }

    if (kt + 1 < NT) { c0 = nx0; c1 = nx1; cm = nxm; }
  }

  // ---- epilogue: store PARTIAL O^T (bf16, unscaled) + partial l; no atomics ----
  ushort* Pp = hf ? P1 : P0;
  float* lp = hf ? l1 : l0;
#pragma unroll
  for (int dt = 0; dt < 4; ++dt) {
    uint2 uv;
    uv.x = pk2(o[dt][0], o[dt][1]);
    uv.y = pk2(o[dt][2], o[dt][3]);
    *(uint2*)(Pp + (size_t)(b * N_ + q0 + (w << 4) + c) * D_ + h * 64 + dt * 16 + quad * 4) = uv;
  }
  if (quad == 0) lp[((b * H_ + h) << 11) + q0 + (w << 4) + c] = o5[0];
}

extern "C" void kernel_launch(void* const* d_in, const int* in_sizes, int n_in,
                              void* d_out, int out_size, void* d_ws, size_t ws_size,
                              hipStream_t stream) {
  const float* queries = (const float*)d_in[0];
  const int* mask = (const int*)d_in[1];
  const float* Wq = (const float*)d_in[2];
  const float* Wk = (const float*)d_in[3];
  const float* Wc = (const float*)d_in[4];
  float* out = (float*)d_out;

  const size_t nTok = (size_t)B_ * N_;
  const size_t nXD = nTok * D_;
  const size_t nW = (size_t)D_ * D_;
  ushort* Xb = (ushort*)d_ws;
  ushort* Wqb = Xb + nXD;     // Wq|Wk|Wc contiguous
  ushort* Wkb = Wqb + nW;
  ushort* Wcb = Wkb + nW;
  ushort* Qb = Wcb + nW;
  ushort* Kb = Qb + nXD;
  ushort* Ab = Kb + nXD;
  uint32_t* pk = (uint32_t*)(Ab + nXD);
  // dead-region reuse during attn (all within verified footprint):
  ushort* P0 = Xb;            // bf16 partial O, half 0 (Xb dead after gemm<0>)
  ushort* P1 = Ab;            // bf16 partial O, half 1 (merged in-place into Ab)
  float* l0 = (float*)Wqb;    // 256 KB in dead Wqb (512 KB)
  float* l1 = (float*)Wkb;    // 256 KB in dead Wkb

  prep<<<3168, 256, 0, stream>>>(queries, mask, Wq, Wk, Wc, Xb, Wqb, pk);
  gemm128<0><<<dim3(D_ / 128, (int)(nTok / 128), 2), 256, 0, stream>>>(
      Xb, Wqb, Wkb, Qb, Kb, NORM2_, 1.0f);
  attn_mfma<<<dim3(64, H_, B_), 256, 0, stream>>>(Qb, Kb, pk, P0, P1, l0, l1);
  merge<<<2048, 256, 0, stream>>>(P0, l0, l1, Ab);
  gemm128<1><<<dim3(D_ / 128, (int)(nTok / 128), 1), 256, 0, stream>>>(
      Ab, Wcb, nullptr, out, nullptr, 1.0f, 1.0f);
}

// Round 10
// 207.425 us; speedup vs baseline: 1.1965x; 1.0105x over previous
//
#include <hip/hip_runtime.h>
#include <hip/hip_bf16.h>
#include <math.h>

#define B_ 4
#define N_ 2048
#define D_ 512
#define H_ 8
// NORM * log2(e): scores pre-scaled so softmax uses exp2 directly.
#define NORM2_ 0.18033688011112042f

typedef __attribute__((ext_vector_type(8))) short short8;   // 8 bf16 (4 VGPRs)
typedef __attribute__((ext_vector_type(4))) float f32x4;    // MFMA C/D
#define MFMA16(a, b, c) __builtin_amdgcn_mfma_f32_16x16x32_bf16(a, b, c, 0, 0, 0)
#define EXP2(x) __builtin_amdgcn_exp2f(x)

// pack two f32 -> two bf16 (RNE, native v_cvt_pk_bf16_f32); .x at low half
static __device__ __forceinline__ uint32_t pk2(float lo, float hi) {
  __hip_bfloat162 h = __float22bfloat162_rn(make_float2(lo, hi));
  return *(reinterpret_cast<uint32_t*>(&h));
}

// async global->LDS, 16B per lane. LDS dest must be wave-uniform base + lane*16.
static __device__ __forceinline__ void async16(const ushort* lds, const ushort* g) {
  __builtin_amdgcn_global_load_lds(
      (const __attribute__((address_space(1))) uint32_t*)g,
      (__attribute__((address_space(3))) uint32_t*)(ushort*)lds, 16, 0, 0);
}

// ---------------- fused prep: mask pack + all fp32->bf16 conversions (r1-verified) -----------
__global__ __launch_bounds__(256) void prep(const float* __restrict__ q,
                                            const int* __restrict__ mask,
                                            const float* __restrict__ wq,
                                            const float* __restrict__ wk,
                                            const float* __restrict__ wc,
                                            ushort* __restrict__ Xb,
                                            ushort* __restrict__ Wb,
                                            uint32_t* __restrict__ pk) {
  const int bx = blockIdx.x;
  if (bx < 2048) {
    const int lane = threadIdx.x & 63;
    const int wid = ((bx << 8) + threadIdx.x) >> 6;  // 8192 waves
    for (int i = wid; i < 65536; i += 8192) {        // 256-key chunks
      const int4 m = ((const int4*)mask)[(size_t)i * 64 + lane];
      uint32_t nib = (uint32_t)(m.x != 0) | ((uint32_t)(m.y != 0) << 1) |
                     ((uint32_t)(m.z != 0) << 2) | ((uint32_t)(m.w != 0) << 3);
      nib |= __shfl_xor(nib, 1) << 4;
      nib |= __shfl_xor(nib, 2) << 8;
      nib |= __shfl_xor(nib, 4) << 16;
      if ((lane & 7) == 0) pk[i * 8 + (lane >> 3)] = nib;
    }
  } else if (bx < 3072) {
    const int i = ((bx - 2048) << 8) + threadIdx.x;
    for (int j = i; j < 1048576; j += 262144) {
      const float4 v = ((const float4*)q)[j];
      uint2 o; o.x = pk2(v.x, v.y); o.y = pk2(v.z, v.w);
      ((uint2*)Xb)[j] = o;
    }
  } else {
    const int i = ((bx - 3072) << 8) + threadIdx.x;
    for (int j = i; j < 196608; j += 24576) {
      const int wi = j >> 16, off = j & 65535;
      const float* src = (wi == 0) ? wq : (wi == 1) ? wk : wc;
      const float4 v = ((const float4*)src)[off];
      uint2 o; o.x = pk2(v.x, v.y); o.y = pk2(v.z, v.w);
      ((uint2*)Wb)[j] = o;
    }
  }
}

// ---------------- merge: Ab = bf16((P0 + P1) / (l0 + l1)), in-place over P1 ----------------
__global__ __launch_bounds__(256) void merge(const ushort* __restrict__ P0,
                                             const float* __restrict__ l0,
                                             const float* __restrict__ l1,
                                             ushort* __restrict__ Ab) {
  const int j = (blockIdx.x << 8) + threadIdx.x;  // 0..524287, 8 bf16 each
  const int h = (j >> 3) & 7;
  const int tok = j >> 6;                          // b*N + n
  const int b = tok >> 11, n = tok & 2047;
  const int li = ((b * H_ + h) << 11) + n;
  const float inv = 1.f / (l0[li] + l1[li]);
  const uint4 a0 = ((const uint4*)P0)[j];
  const uint4 a1 = ((const uint4*)Ab)[j];  // P1 aliases Ab
  uint4 o;
  const uint32_t* u0 = (const uint32_t*)&a0;
  const uint32_t* u1 = (const uint32_t*)&a1;
  uint32_t* uo = (uint32_t*)&o;
#pragma unroll
  for (int m = 0; m < 4; ++m) {
    const float lo = __uint_as_float(u0[m] << 16) + __uint_as_float(u1[m] << 16);
    const float hi = __uint_as_float(u0[m] & 0xFFFF0000u) +
                     __uint_as_float(u1[m] & 0xFFFF0000u);
    uo[m] = pk2(lo * inv, hi * inv);
  }
  ((uint4*)Ab)[j] = o;
}

// ---------------- 128x128 bf16 MFMA GEMM: C = X @ W^T (r9-verified 2-phase) ----------------
template <int F32OUT>
__global__ __launch_bounds__(256) void gemm128(const ushort* __restrict__ X,
                                               const ushort* __restrict__ W0,
                                               const ushort* __restrict__ W1,
                                               void* __restrict__ C0,
                                               void* __restrict__ C1,
                                               float s0, float s1) {
  const ushort* Wp = (blockIdx.z == 0) ? W0 : W1;
  void* Cp = (blockIdx.z == 0) ? C0 : C1;
  const float sc = (blockIdx.z == 0) ? s0 : s1;
  const int t = threadIdx.x;
  const int w = t >> 6, lane = t & 63, quad = lane >> 4, c = lane & 15;
  const int wm = w & 1, wn = w >> 1;
  const int n0 = blockIdx.x * 128, m0 = blockIdx.y * 128;
  __shared__ __align__(16) ushort Xs[2][128][64];
  __shared__ __align__(16) ushort Ws[2][128][64];
  f32x4 acc[4][4];
#pragma unroll
  for (int i = 0; i < 4; ++i)
#pragma unroll
    for (int j = 0; j < 4; ++j) acc[i][j] = (f32x4){0.f, 0.f, 0.f, 0.f};

#define GSTAGE(bf, k0)                                                        \
  do {                                                                        \
    _Pragma("unroll") for (int g = 0; g < 4; ++g) {                           \
      const int id = w * 256 + g * 64 + lane;                                 \
      const int row = id >> 3, lch = id & 7;                                  \
      const int gch = lch ^ (row & 7);                                        \
      async16(&Xs[bf][row][lch * 8], X + (size_t)(m0 + row) * D_ + (k0) + gch * 8); \
      async16(&Ws[bf][row][lch * 8], Wp + (size_t)(n0 + row) * D_ + (k0) + gch * 8); \
    }                                                                         \
  } while (0)

  GSTAGE(0, 0);
  __syncthreads();  // buf0 landed (implicit vmcnt drain)
  const int NK = D_ / 64;  // 8
  for (int kt = 0; kt < NK; ++kt) {
    const int bf = kt & 1;
    if (kt + 1 < NK) GSTAGE(bf ^ 1, (kt + 1) * 64);  // prefetch next (hidden under MFMA)
#pragma unroll
    for (int s = 0; s < 2; ++s) {
      short8 af[4], bt[4];
#pragma unroll
      for (int i = 0; i < 4; ++i) {
        const int rA = wn * 64 + i * 16 + c;
        af[i] = *(const short8*)&Ws[bf][rA][(((s * 4 + quad) ^ (rA & 7)) & 7) * 8];
        const int rB = wm * 64 + i * 16 + c;
        bt[i] = *(const short8*)&Xs[bf][rB][(((s * 4 + quad) ^ (rB & 7)) & 7) * 8];
      }
#pragma unroll
      for (int i = 0; i < 4; ++i)
#pragma unroll
        for (int j = 0; j < 4; ++j) acc[i][j] = MFMA16(af[i], bt[j], acc[i][j]);
    }
    if (kt + 1 < NK) __syncthreads();  // drain prefetch + protect buf reuse
  }
#undef GSTAGE
#pragma unroll
  for (int i = 0; i < 4; ++i)
#pragma unroll
    for (int j = 0; j < 4; ++j) {
      const size_t off =
          (size_t)(m0 + wm * 64 + j * 16 + c) * D_ + n0 + wn * 64 + i * 16 + quad * 4;
      if (F32OUT) {
        float4 v; v.x = acc[i][j][0]; v.y = acc[i][j][1]; v.z = acc[i][j][2]; v.w = acc[i][j][3];
        *(float4*)((float*)Cp + off) = v;
      } else {
        uint2 uv;
        uv.x = pk2(acc[i][j][0] * sc, acc[i][j][1] * sc);
        uv.y = pk2(acc[i][j][2] * sc, acc[i][j][3] * sc);
        *(uint2*)((ushort*)Cp + off) = uv;
      }
    }
}

// ---------------- flash attention: 8-wave / 128-q blocks for full occupancy ----------------
// r8-verified core; change = two q-tiles share one block so Ks/KtU (16 KB) is
// amortized over 8 waves. LDS 34 KB -> 4 blocks/CU x 8 waves = 32 waves/CU
// (100%), entire 1024-block grid resident in one scheduling round.
// Staging path byte-identical (threads 0..255 run the old 2-rows-per-thread
// STAGE; waves 4..7 compute only). Key-split x2 + merge kept from r8.
__global__ __launch_bounds__(512) void attn_mfma(const ushort* __restrict__ Qb,
                                                 const ushort* __restrict__ Kb,
                                                 const uint32_t* __restrict__ pk,
                                                 ushort* __restrict__ P0,
                                                 ushort* __restrict__ P1,
                                                 float* __restrict__ l0,
                                                 float* __restrict__ l1) {
  const int qt128 = blockIdx.x >> 1, hf = blockIdx.x & 1;
  const int h = blockIdx.y, b = blockIdx.z;
  const int q0 = qt128 * 128;
  const int t = threadIdx.x;
  const int w = t >> 6, lane = t & 63, quad = lane >> 4, c = lane & 15;

  __shared__ __align__(16) ushort Ks[64][64];        // 8K: K rows, swizzled chunks
  __shared__ __align__(16) uint32_t KtU[64][32];     // 8K: V^T key-pair u32, swizzled
  __shared__ __align__(16) ushort QP[8][16][72];     // 18.4K: Qs[128][64] then Pq
  ushort(*Qs)[64] = (ushort(*)[64]) & QP[0][0][0];
  ushort(*Pq)[16][72] = QP;

  // ---- stage Q once (async DMA): 128 rows x 64 = 1024 chunks / 512 threads ----
#pragma unroll
  for (int p = 0; p < 2; ++p) {
    const int id = t + p * 512;
    const int row = id >> 3, lch = id & 7, gch = lch ^ (row & 7);
    async16(&Qs[row][lch * 8], Qb + (size_t)(b * N_ + q0 + row) * D_ + h * 64 + gch * 8);
  }
  __syncthreads();
  const int rq = (w << 4) + c;  // 0..127
  const short8 bq0 = *(const short8*)&Qs[rq][((quad ^ (rq & 7)) & 7) * 8];
  const short8 bq1 = *(const short8*)&Qs[rq][(((4 + quad) ^ (rq & 7)) & 7) * 8];

  short8 vones;
#pragma unroll
  for (int i = 0; i < 8; ++i) vones[i] = (short)0x3F80;  // bf16 1.0 splat

  f32x4 o[4];
#pragma unroll
  for (int i = 0; i < 4; ++i) o[i] = (f32x4){0.f, 0.f, 0.f, 0.f};
  f32x4 o5 = (f32x4){0.f, 0.f, 0.f, 0.f};  // l accumulator (ones-MFMA, rows identical)

  // staging roles (threads 0..255 only): key-pair, d-chunk — r8-verified path
  const int kp = t >> 3, ch = t & 7;
  const int r0 = 2 * kp, r1 = r0 + 1;
  const int ksw0 = ((ch ^ (r0 & 7)) & 7) * 8, ksw1 = ((ch ^ (r1 & 7)) & 7) * 8;
  const ushort* kb0 =
      Kb + (size_t)(b * N_ + hf * 1024 + 2 * kp) * D_ + h * 64 + ch * 8;
  const uint32_t* pkq =
      pk + ((size_t)(b * N_ + q0 + (w << 4) + c) << 6) + hf * 32;

  // prefetched tile data (registers; c0/c1 meaningful for t<256 only)
  uint4 c0, c1;
  if (t < 256) {
    c0 = *(const uint4*)kb0;
    c1 = *(const uint4*)(kb0 + D_);
  }
  uint2 cm = *(const uint2*)pkq;
  uint4 nx0, nx1; uint2 nxm;

  const int NT = 16;  // half the keys
  for (int kt = 0; kt < NT; ++kt) {
    __syncthreads();  // prior tile's frag reads (and initial Qs reads) done
    // ---- stage K tile from registers (rows + u32 key-pair transpose), t<256 ----
    if (t < 256) {
      *(uint4*)&Ks[r0][ksw0] = c0;
      *(uint4*)&Ks[r1][ksw1] = c1;
      const uint32_t* a0 = (const uint32_t*)&c0;
      const uint32_t* a1 = (const uint32_t*)&c1;
#pragma unroll
      for (int m = 0; m < 4; ++m) {
        const uint32_t lo = __builtin_amdgcn_perm(a1[m], a0[m], 0x05040100);  // even d
        const uint32_t hi = __builtin_amdgcn_perm(a1[m], a0[m], 0x07060302);  // odd d
        const int j0 = 2 * m, j1 = 2 * m + 1;
        KtU[ch * 8 + j0][(kp & 3) | ((((kp >> 2) ^ j0 ^ ch) & 7) << 2)] = lo;
        KtU[ch * 8 + j1][(kp & 3) | ((((kp >> 2) ^ j1 ^ ch) & 7) << 2)] = hi;
      }
    }
    __syncthreads();

    if (kt + 1 < NT) {  // prefetch next tile while computing
      if (t < 256) {
        const ushort* kbn = kb0 + (size_t)(kt + 1) * 64 * D_;
        nx0 = *(const uint4*)kbn;
        nx1 = *(const uint4*)(kbn + D_);
      }
      nxm = *(const uint2*)(pkq + (kt + 1) * 2);
    }

    // ---- S^T = K·Q^T; p = masked ? 0 : exp2(s) ----
#pragma unroll
    for (int tI = 0; tI < 4; ++tI) {
      const int rk = tI * 16 + c;
      const short8 aK0 = *(const short8*)&Ks[rk][((quad ^ (rk & 7)) & 7) * 8];
      const short8 aK1 = *(const short8*)&Ks[rk][(((4 + quad) ^ (rk & 7)) & 7) * 8];
      f32x4 z = (f32x4){0.f, 0.f, 0.f, 0.f};
      z = MFMA16(aK0, bq0, z);
      z = MFMA16(aK1, bq1, z);
      const uint32_t mw = (tI < 2) ? cm.x : cm.y;
      const int bb = ((tI & 1) << 4) + quad * 4;
      uint32_t pb[4];
#pragma unroll
      for (int r = 0; r < 4; ++r) {
        const float e = EXP2(z[r]);                       // unconditional
        pb[r] = ((mw >> (bb + r)) & 1u) ? 0u : __float_as_uint(e);
      }
      const uint32_t pw0 = __builtin_amdgcn_perm(pb[1], pb[0], 0x07060302);
      const uint32_t pw1 = __builtin_amdgcn_perm(pb[3], pb[2], 0x07060302);
      *(uint2*)&Pq[w][c][tI * 16 + quad * 4] = make_uint2(pw0, pw1);
    }

    // ---- O^T += V^T·P^T ; l via ones-MFMA ----
    const short8 bp0 = *(const short8*)&Pq[w][c][quad * 8];
    const short8 bp1 = *(const short8*)&Pq[w][c][32 + quad * 8];
    o5 = MFMA16(vones, bp0, o5);
    o5 = MFMA16(vones, bp1, o5);
#pragma unroll
    for (int dt = 0; dt < 4; ++dt) {
      const int dd = dt * 16 + c;
      const int g = (c & 7) ^ ((2 * dt + (c >> 3)) & 7);
      const short8 aV0 = *(const short8*)&KtU[dd][((quad ^ g) & 7) << 2];
      const short8 aV1 = *(const short8*)&KtU[dd][(((4 + quad) ^ g) & 7) << 2];
      o[dt] = MFMA16(aV0, bp0, o[dt]);
      o[dt] = MFMA16(aV1, bp1, o[dt]);
    }

    if (kt + 1 < NT) {
      if (t < 256) { c0 = nx0; c1 = nx1; }
      cm = nxm;
    }
  }

  // ---- epilogue: store PARTIAL O^T (bf16, unscaled) + partial l; no atomics ----
  ushort* Pp = hf ? P1 : P0;
  float* lp = hf ? l1 : l0;
#pragma unroll
  for (int dt = 0; dt < 4; ++dt) {
    uint2 uv;
    uv.x = pk2(o[dt][0], o[dt][1]);
    uv.y = pk2(o[dt][2], o[dt][3]);
    *(uint2*)(Pp + (size_t)(b * N_ + q0 + (w << 4) + c) * D_ + h * 64 + dt * 16 + quad * 4) = uv;
  }
  if (quad == 0) lp[((b * H_ + h) << 11) + q0 + (w << 4) + c] = o5[0];
}

extern "C" void kernel_launch(void* const* d_in, const int* in_sizes, int n_in,
                              void* d_out, int out_size, void* d_ws, size_t ws_size,
                              hipStream_t stream) {
  const float* queries = (const float*)d_in[0];
  const int* mask = (const int*)d_in[1];
  const float* Wq = (const float*)d_in[2];
  const float* Wk = (const float*)d_in[3];
  const float* Wc = (const float*)d_in[4];
  float* out = (float*)d_out;

  const size_t nTok = (size_t)B_ * N_;
  const size_t nXD = nTok * D_;
  const size_t nW = (size_t)D_ * D_;
  ushort* Xb = (ushort*)d_ws;
  ushort* Wqb = Xb + nXD;     // Wq|Wk|Wc contiguous
  ushort* Wkb = Wqb + nW;
  ushort* Wcb = Wkb + nW;
  ushort* Qb = Wcb + nW;
  ushort* Kb = Qb + nXD;
  ushort* Ab = Kb + nXD;
  uint32_t* pk = (uint32_t*)(Ab + nXD);
  // dead-region reuse during attn (all within verified footprint):
  ushort* P0 = Xb;            // bf16 partial O, half 0 (Xb dead after gemm<0>)
  ushort* P1 = Ab;            // bf16 partial O, half 1 (merged in-place into Ab)
  float* l0 = (float*)Wqb;    // 256 KB in dead Wqb (512 KB)
  float* l1 = (float*)Wkb;    // 256 KB in dead Wkb

  prep<<<3168, 256, 0, stream>>>(queries, mask, Wq, Wk, Wc, Xb, Wqb, pk);
  gemm128<0><<<dim3(D_ / 128, (int)(nTok / 128), 2), 256, 0, stream>>>(
      Xb, Wqb, Wkb, Qb, Kb, NORM2_, 1.0f);
  attn_mfma<<<dim3(32, H_, B_), 512, 0, stream>>>(Qb, Kb, pk, P0, P1, l0, l1);
  merge<<<2048, 256, 0, stream>>>(P0, l0, l1, Ab);
  gemm128<1><<<dim3(D_ / 128, (int)(nTok / 128), 1), 256, 0, stream>>>(
      Ab, Wcb, nullptr, out, nullptr, 1.0f, 1.0f);
}